// Round 2
// baseline (101.678 us; speedup 1.0000x reference)
//
#include <hip/hip_runtime.h>

// L0ConjunctionLayer: out[b,o] = prod_i (1 - (1 - x[b,i]*z[i]) * w[i,o])
// z[i] = clamp(sigmoid(qz_loga[i]) * 1.2 - 0.1, 0, 1)
// B=2048, I=512, O=256, fp32.
//
// R1 design: SGPR-broadcast w. Block = 4 waves; lane <-> b-row (64 rows),
// wave <-> o-group of 4 columns -> 64x16 tile, grid 32x16 = 512 blocks
// (2 blocks/CU, 8 waves/CU, 2 waves/SIMD). w[k, o0:o0+4] is wave-uniform ->
// scalar loads (s_load_dwordx4), zero LDS traffic for w. y = 1 - x*z staged
// in LDS packed float4-per-4k so the inner read is one ds_read_b128 per
// 4 k-steps (bytes-floor, conflict-free). VALU floor: 2 ops/element ->
// 536M lane-ops -> ~16.4k cyc/CU ~ 8 us.

#define DIM_B 2048
#define DIM_I 512
#define DIM_O 256
#define TILE_B 64
#define TILE_O 16
#define BK 64

__global__ __launch_bounds__(256, 2) void l0conj_kernel(
    const float* __restrict__ x,      // [B, I]
    const float* __restrict__ w,      // [I, O]
    const float* __restrict__ qz,     // [I]
    float* __restrict__ out)          // [B, O]
{
    __shared__ float zS[DIM_I];
    __shared__ float4 yS[BK / 4][TILE_B];  // [k4][b], 16 KB

    const int t = threadIdx.x;
    const int lane = t & 63;
    const int bBase = blockIdx.x * TILE_B;
    const int oBase = blockIdx.y * TILE_O;
    // Wave-uniform o-column base, forced into an SGPR so w addressing is
    // provably scalar -> s_load.
    const int o0 = __builtin_amdgcn_readfirstlane(oBase + ((t >> 6) << 2));

    // Per-block gate precompute.
    for (int i = t; i < DIM_I; i += 256) {
        float q = qz[i];
        float sig = 1.0f / (1.0f + __expf(-q));
        float z = fmaf(sig, 1.2f, -0.1f);
        zS[i] = fminf(fmaxf(z, 0.0f), 1.0f);
    }
    __syncthreads();

    // Staging mapping: row sr = t>>2 (0..63), k-offset sc = (t&3)*16.
    const int sr = t >> 2;
    const int sc = (t & 3) * 16;

    float4 acc = make_float4(1.0f, 1.0f, 1.0f, 1.0f);

    for (int k0 = 0; k0 < DIM_I; k0 += BK) {
        // ---- stage y = 1 - x*z into yS, packed 4 consecutive k per float4
        const float4* xp = (const float4*)(x + (size_t)(bBase + sr) * DIM_I + k0 + sc);
        const float4* zp = (const float4*)(&zS[k0 + sc]);
        float4 xv[4], zv[4];
#pragma unroll
        for (int i = 0; i < 4; ++i) xv[i] = xp[i];
#pragma unroll
        for (int i = 0; i < 4; ++i) zv[i] = zp[i];
#pragma unroll
        for (int i = 0; i < 4; ++i) {
            float4 yv;
            yv.x = fmaf(-xv[i].x, zv[i].x, 1.0f);
            yv.y = fmaf(-xv[i].y, zv[i].y, 1.0f);
            yv.z = fmaf(-xv[i].z, zv[i].z, 1.0f);
            yv.w = fmaf(-xv[i].w, zv[i].w, 1.0f);
            yS[(sc >> 2) + i][sr] = yv;
        }
        __syncthreads();

        // ---- inner product-accumulate: 16 k4 steps x (4 k x 4 o)
#pragma unroll
        for (int k4 = 0; k4 < BK / 4; ++k4) {
            const float4 y = yS[k4][lane];
            const int kk = k0 + k4 * 4;
            // wave-uniform scalar loads of w rows kk..kk+3, cols o0..o0+3
            const float4 w0 = *(const float4*)(w + (size_t)(kk + 0) * DIM_O + o0);
            const float4 w1 = *(const float4*)(w + (size_t)(kk + 1) * DIM_O + o0);
            const float4 w2 = *(const float4*)(w + (size_t)(kk + 2) * DIM_O + o0);
            const float4 w3 = *(const float4*)(w + (size_t)(kk + 3) * DIM_O + o0);

            acc.x *= fmaf(-y.x, w0.x, 1.0f);
            acc.y *= fmaf(-y.x, w0.y, 1.0f);
            acc.z *= fmaf(-y.x, w0.z, 1.0f);
            acc.w *= fmaf(-y.x, w0.w, 1.0f);

            acc.x *= fmaf(-y.y, w1.x, 1.0f);
            acc.y *= fmaf(-y.y, w1.y, 1.0f);
            acc.z *= fmaf(-y.y, w1.z, 1.0f);
            acc.w *= fmaf(-y.y, w1.w, 1.0f);

            acc.x *= fmaf(-y.z, w2.x, 1.0f);
            acc.y *= fmaf(-y.z, w2.y, 1.0f);
            acc.z *= fmaf(-y.z, w2.z, 1.0f);
            acc.w *= fmaf(-y.z, w2.w, 1.0f);

            acc.x *= fmaf(-y.w, w3.x, 1.0f);
            acc.y *= fmaf(-y.w, w3.y, 1.0f);
            acc.z *= fmaf(-y.w, w3.z, 1.0f);
            acc.w *= fmaf(-y.w, w3.w, 1.0f);
        }
        __syncthreads();
    }

    *(float4*)(out + (size_t)(bBase + lane) * DIM_O + o0) = acc;
}

extern "C" void kernel_launch(void* const* d_in, const int* in_sizes, int n_in,
                              void* d_out, int out_size, void* d_ws, size_t ws_size,
                              hipStream_t stream) {
    const float* x = (const float*)d_in[0];   // [2048, 512]
    const float* w = (const float*)d_in[1];   // [512, 256]
    const float* qz = (const float*)d_in[2];  // [512]
    float* out = (float*)d_out;               // [2048, 256]

    dim3 grid(DIM_B / TILE_B, DIM_O / TILE_O);  // (32, 16) = 512 blocks
    dim3 block(256);
    l0conj_kernel<<<grid, block, 0, stream>>>(x, w, qz, out);
}

// Round 3
// 75.069 us; speedup vs baseline: 1.3545x; 1.3545x over previous
//
#include <hip/hip_runtime.h>

// L0ConjunctionLayer: out[b,o] = prod_k (1 - y[b,k]*w[k,o]),  y = 1 - x*z,
// z[k] = clamp(sigmoid(qz[k])*1.2 - 0.1, 0, 1).  B=2048, K=512, O=256, fp32.
//
// R3: lane <-> o orientation kills the transpose problem entirely.
//  K1: y = 1 - x*z -> d_ws (coalesced float4, ~2 us).
//  K2: 256 blocks x 1024 thr. wave ww: og=ww&3 (o-group of 64), kq=ww>>2
//      (k-quarter of 128). Thread: 8 b-rows x 1 o x 128 k.
//      - w[k][og*64+lane]: contiguous global loads (w's native layout), L2-hot.
//      - y[b][k]: wave-uniform address -> s_load_dwordx4 (scalar pipe, free).
//      - math as float2 -> v_pk_fma_f32 / v_pk_mul_f32 (2x VALU).
//      - split-K x4 partial products combined via 32 KB LDS epilogue.
//      VALU floor ~8.2k cyc/CU ~ 4 us; w L2 traffic 128 MB ~ 3.5 us (overlapped).

typedef float v2f __attribute__((ext_vector_type(2)));

#define DIM_B 2048
#define DIM_I 512
#define DIM_O 256

__global__ __launch_bounds__(256) void l0conj_prep(
    const float* __restrict__ x,      // [B, I]
    const float* __restrict__ qz,     // [I]
    float* __restrict__ y)            // [B, I] workspace
{
    const int f = blockIdx.x * 256 + threadIdx.x;    // float4 index
    const float4 xv = ((const float4*)x)[f];
    const int k = (f * 4) & (DIM_I - 1);
    const float4 qv = *(const float4*)(qz + k);
    float4 yv;
    {
        float s0 = 1.0f / (1.0f + __expf(-qv.x));
        float s1 = 1.0f / (1.0f + __expf(-qv.y));
        float s2 = 1.0f / (1.0f + __expf(-qv.z));
        float s3 = 1.0f / (1.0f + __expf(-qv.w));
        float z0 = fminf(fmaxf(fmaf(s0, 1.2f, -0.1f), 0.0f), 1.0f);
        float z1 = fminf(fmaxf(fmaf(s1, 1.2f, -0.1f), 0.0f), 1.0f);
        float z2 = fminf(fmaxf(fmaf(s2, 1.2f, -0.1f), 0.0f), 1.0f);
        float z3 = fminf(fmaxf(fmaf(s3, 1.2f, -0.1f), 0.0f), 1.0f);
        yv.x = fmaf(-xv.x, z0, 1.0f);
        yv.y = fmaf(-xv.y, z1, 1.0f);
        yv.z = fmaf(-xv.z, z2, 1.0f);
        yv.w = fmaf(-xv.w, z3, 1.0f);
    }
    ((float4*)y)[f] = yv;
}

__global__ __launch_bounds__(1024, 1) void l0conj_main(
    const float* __restrict__ w,      // [I, O]
    const float* __restrict__ y,      // [B, I] (from K1)
    float* __restrict__ out)          // [B, O]
{
    __shared__ float pS[4][8][DIM_O];  // 32 KB split-K partials

    const int t = threadIdx.x;
    const int lane = t & 63;
    const int ww = __builtin_amdgcn_readfirstlane(t >> 6);  // wave id 0..15
    const int og = ww & 3;        // o-group (64 cols)
    const int kq = ww >> 2;       // k-quarter (128 k's)
    const int o = og * 64 + lane;
    const int bBase = blockIdx.x * 8;

    // Wave-uniform y base for this block's rows / this wave's k-quarter.
    const float* yq = y + (size_t)bBase * DIM_I + kq * 128;
    const float* wq = w + (size_t)(kq * 128) * DIM_O + o;

    v2f accA[8], accB[8];  // k-parity product pairs per row
#pragma unroll
    for (int r = 0; r < 8; ++r) {
        accA[r] = (v2f){1.0f, 1.0f};
        accB[r] = (v2f){1.0f, 1.0f};
    }

    const v2f one2 = {1.0f, 1.0f};

#pragma unroll 2
    for (int k4 = 0; k4 < 32; ++k4) {
        // w fragment: 4 consecutive k's of this lane's o column (stride O).
        const float* wp = wq + (size_t)(k4 * 4) * DIM_O;
        const float w0 = wp[0];
        const float w1 = wp[DIM_O];
        const float w2 = wp[2 * DIM_O];
        const float w3 = wp[3 * DIM_O];
        const v2f wA = {w0, w1};
        const v2f wB = {w2, w3};

#pragma unroll
        for (int r = 0; r < 8; ++r) {
            // Wave-uniform address -> s_load_dwordx4 (scalar broadcast).
            const float4 y4 = *(const float4*)(yq + (size_t)r * DIM_I + k4 * 4);
            const v2f yA = {y4.x, y4.y};
            const v2f yB = {y4.z, y4.w};
            const v2f tA = __builtin_elementwise_fma(-yA, wA, one2);
            const v2f tB = __builtin_elementwise_fma(-yB, wB, one2);
            accA[r] *= tA;   // v_pk_mul_f32
            accB[r] *= tB;
        }
    }

    // Write this wave's partial products.
#pragma unroll
    for (int r = 0; r < 8; ++r)
        pS[kq][r][o] = (accA[r].x * accA[r].y) * (accB[r].x * accB[r].y);
    __syncthreads();

    // Combine the 4 k-quarters; waves 0..3 cover all 256 o columns.
    if (ww < 4) {
#pragma unroll
        for (int r = 0; r < 8; ++r) {
            float p = pS[0][r][o] * pS[1][r][o] * pS[2][r][o] * pS[3][r][o];
            out[(size_t)(bBase + r) * DIM_O + o] = p;
        }
    }
}

extern "C" void kernel_launch(void* const* d_in, const int* in_sizes, int n_in,
                              void* d_out, int out_size, void* d_ws, size_t ws_size,
                              hipStream_t stream) {
    const float* x = (const float*)d_in[0];   // [2048, 512]
    const float* w = (const float*)d_in[1];   // [512, 256]
    const float* qz = (const float*)d_in[2];  // [512]
    float* out = (float*)d_out;               // [2048, 256]
    float* yws = (float*)d_ws;                // [2048, 512] scratch (4 MB)

    l0conj_prep<<<dim3(DIM_B * DIM_I / 4 / 256), dim3(256), 0, stream>>>(x, qz, yws);
    l0conj_main<<<dim3(DIM_B / 8), dim3(1024), 0, stream>>>(w, yws, out);
}